// Round 1
// baseline (2118.329 us; speedup 1.0000x reference)
//
#include <hip/hip_runtime.h>

typedef __attribute__((ext_vector_type(8))) short short8;
typedef __attribute__((ext_vector_type(4))) float f32x4;

#define NTOK 12000
#define APAD 25088   // 196 * 128 padded assignment rows
#define NRB  196
#define NASN 24000   // 12000 tokens * top-2

__device__ __forceinline__ void async_ld16(const void* g, void* l){
  __builtin_amdgcn_global_load_lds(
      (const __attribute__((address_space(1))) void*)g,
      (__attribute__((address_space(3))) void*)l, 16, 0, 0);
}

__device__ __forceinline__ unsigned short f2bf(float f){
  union { float f; unsigned int u; } v; v.f = f;
  return (unsigned short)((v.u + 0x7FFFu + ((v.u >> 16) & 1u)) >> 16);
}

__device__ __forceinline__ float block_sum256(float v){
#pragma unroll
  for (int off = 32; off; off >>= 1) v += __shfl_xor(v, off);
  __shared__ float s[4];
  if ((threadIdx.x & 63) == 0) s[threadIdx.x >> 6] = v;
  __syncthreads();
  return s[0] + s[1] + s[2] + s[3];
}

// ---------------- fp32 -> bf16 tensor conversion (grid-stride) ------------
__global__ __launch_bounds__(256) void k_cvt(
    const float4* __restrict__ src, ushort4* __restrict__ dst, int n4)
{
  int i = blockIdx.x * 256 + threadIdx.x;
  const int stride = gridDim.x * 256;
  for (; i < n4; i += stride){
    float4 v = src[i];
    ushort4 o;
    o.x = f2bf(v.x); o.y = f2bf(v.y); o.z = f2bf(v.z); o.w = f2bf(v.w);
    dst[i] = o;
  }
}

// ---------------- RMSNorm (pre) + cast to bf16; one block per token row ----
__global__ __launch_bounds__(256) void k_rmsnorm_pre(
    const float* __restrict__ x, const float* __restrict__ w,
    unsigned short* __restrict__ nx)
{
  const int row = blockIdx.x, tid = threadIdx.x;
  const float* xr = x + (long)row * 2048;
  float4 a = ((const float4*)xr)[tid];
  float4 b = ((const float4*)xr)[tid + 256];
  float ss = a.x*a.x + a.y*a.y + a.z*a.z + a.w*a.w
           + b.x*b.x + b.y*b.y + b.z*b.z + b.w*b.w;
  ss = block_sum256(ss);
  float sc = rsqrtf(ss * (1.f / 2048.f) + 1e-6f);
  float4 wa = ((const float4*)w)[tid];
  float4 wb = ((const float4*)w)[tid + 256];
  ushort4 oa, ob;
  oa.x = f2bf(a.x * sc * wa.x); oa.y = f2bf(a.y * sc * wa.y);
  oa.z = f2bf(a.z * sc * wa.z); oa.w = f2bf(a.w * sc * wa.w);
  ob.x = f2bf(b.x * sc * wb.x); ob.y = f2bf(b.y * sc * wb.y);
  ob.z = f2bf(b.z * sc * wb.z); ob.w = f2bf(b.w * sc * wb.w);
  ((ushort4*)(nx + (long)row * 2048))[tid] = oa;
  ((ushort4*)(nx + (long)row * 2048))[tid + 256] = ob;
}

// ---------------- normalize router weights -------------------------------
__global__ __launch_bounds__(256) void k_prep_router(
    const float* __restrict__ rw, float* __restrict__ rwn)
{
  const int e = blockIdx.x, tid = threadIdx.x;
  const float* r = rw + (long)e * 2048;
  float4 a = ((const float4*)r)[tid];
  float4 b = ((const float4*)r)[tid + 256];
  float ss = a.x*a.x + a.y*a.y + a.z*a.z + a.w*a.w
           + b.x*b.x + b.y*b.y + b.z*b.z + b.w*b.w;
  ss = block_sum256(ss);
  float inv = 1.f / sqrtf(ss);
  float4 oa = {a.x*inv, a.y*inv, a.z*inv, a.w*inv};
  float4 ob = {b.x*inv, b.y*inv, b.z*inv, b.w*inv};
  ((float4*)(rwn + (long)e * 2048))[tid] = oa;
  ((float4*)(rwn + (long)e * 2048))[tid + 256] = ob;
}

// ---------------- router: fp32 from x (rms scale cancels in cosine) -------
// one wave per token, 16 tokens per block
__global__ __launch_bounds__(256) void k_router(
    const float* __restrict__ x, const float* __restrict__ lnw,
    const float* __restrict__ rwn, const float* __restrict__ eload,
    int* __restrict__ t2i, float* __restrict__ t2w)
{
  const int lane = threadIdx.x & 63, wid = threadIdx.x >> 6;
#pragma unroll 1
  for (int it = 0; it < 4; ++it){
    const int t = blockIdx.x * 16 + wid * 4 + it;
    const float* xr = x + (long)t * 2048;
    float d0=0,d1=0,d2=0,d3=0,d4=0,d5=0,d6=0,d7=0,ss=0;
#pragma unroll 4
    for (int j = 0; j < 32; ++j){
      int c = j * 64 + lane;
      float v = xr[c] * lnw[c];
      ss += v * v;
      d0 += v * rwn[c];
      d1 += v * rwn[2048 + c];
      d2 += v * rwn[2*2048 + c];
      d3 += v * rwn[3*2048 + c];
      d4 += v * rwn[4*2048 + c];
      d5 += v * rwn[5*2048 + c];
      d6 += v * rwn[6*2048 + c];
      d7 += v * rwn[7*2048 + c];
    }
#pragma unroll
    for (int off = 32; off; off >>= 1){
      ss += __shfl_xor(ss, off);
      d0 += __shfl_xor(d0, off); d1 += __shfl_xor(d1, off);
      d2 += __shfl_xor(d2, off); d3 += __shfl_xor(d3, off);
      d4 += __shfl_xor(d4, off); d5 += __shfl_xor(d5, off);
      d6 += __shfl_xor(d6, off); d7 += __shfl_xor(d7, off);
    }
    if (lane == 0){
      float inv = 1.f / sqrtf(ss);
      float d[8] = {d0,d1,d2,d3,d4,d5,d6,d7};
      float p[8], ch[8];
#pragma unroll
      for (int e = 0; e < 8; ++e){
        float lg = d[e] * inv * 16.f;
        p[e] = 1.f / (1.f + expf(-lg));
        ch[e] = p[e] - 0.5f * eload[e];
      }
      int i0 = 0;
      for (int e = 1; e < 8; ++e) if (ch[e] > ch[i0]) i0 = e;
      int i1 = (i0 == 0) ? 1 : 0;
      for (int e = 0; e < 8; ++e) if (e != i0 && ch[e] > ch[i1]) i1 = e;
      float sum = p[i0] + p[i1] + 1e-20f;
      t2i[t*2]   = i0;  t2i[t*2+1] = i1;
      t2w[t*2]   = p[i0] / sum;
      t2w[t*2+1] = p[i1] / sum;
    }
  }
}

// ---------------- build per-expert assignment segments (single block) -----
__global__ __launch_bounds__(256) void k_build_assign(
    const int* __restrict__ t2i, const float* __restrict__ t2w,
    int* __restrict__ atok, float* __restrict__ awt, int* __restrict__ seg)
{
  __shared__ int cnt[8], offs[8], pc[8], pos[8];
  const int tid = threadIdx.x;
  if (tid < 8){ cnt[tid] = 0; pos[tid] = 0; }
  __syncthreads();
  for (int a = tid; a < NASN; a += 256)
    atomicAdd(&cnt[t2i[a]], 1);
  __syncthreads();
  if (tid == 0){
    int o = 0;
    for (int e = 0; e < 8; ++e){ offs[e] = o; pc[e] = (cnt[e] + 127) & ~127; o += pc[e]; }
  }
  __syncthreads();
  for (int r = tid; r < APAD; r += 256){ atok[r] = 0; awt[r] = 0.f; }
  for (int rb = tid; rb < NRB; rb += 256){
    int e = 0;
    for (int q = 0; q < 8; ++q)
      if (rb * 128 >= offs[q] && rb * 128 < offs[q] + pc[q]) e = q;
    seg[rb] = e;
  }
  __syncthreads();
  for (int a = tid; a < NASN; a += 256){
    int t = a >> 1;
    int e = t2i[a];
    int p = atomicAdd(&pos[e], 1);
    atok[offs[e] + p] = t;
    awt[offs[e] + p]  = t2w[a];
  }
}

// ======================= bf16-weight GEMM path =============================
// GEMM1: act = silu(x@Wg^T) * (x@Wv^T); A bf16 [rows,2048] (opt. gathered),
// B bf16 [4096,2048]; all staging via global_load_lds width=16.
__global__ __launch_bounds__(256) void k_gemm1_bf(
    const unsigned short* __restrict__ A,
    const unsigned short* __restrict__ Bbase, long bstride,
    const int* __restrict__ seg, const int* __restrict__ tok,
    int Mvalid, unsigned short* __restrict__ act)
{
  __shared__ unsigned short lA[128*32];
  __shared__ unsigned short lBg[64*32];
  __shared__ unsigned short lBv[64*32];
  const int tid = threadIdx.x;
  const int bx = blockIdx.x, by = blockIdx.y;
  const unsigned short* B = Bbase + (seg ? (long)seg[by] * bstride : 0L);
  const int m0 = by * 128;

  const int ar0 = m0 + (tid >> 2), ar1 = ar0 + 64;
  const long gr0 = tok ? (long)tok[ar0] : (long)ar0;
  const long gr1 = tok ? (long)tok[ar1] : (long)ar1;
  const unsigned short* ap0 = A + gr0 * 2048 + (tid & 3) * 8;
  const unsigned short* ap1 = A + gr1 * 2048 + (tid & 3) * 8;
  unsigned short* la0 = &lA[tid * 8];
  unsigned short* la1 = &lA[2048 + tid * 8];

  const unsigned short* bg = B + (long)(bx * 64 + (tid >> 2)) * 2048 + (tid & 3) * 8;
  const unsigned short* bv = bg + 2048L * 2048;
  unsigned short* lbg = &lBg[tid * 8];
  unsigned short* lbv = &lBv[tid * 8];

  const int lane = tid & 63, wv = tid >> 6;
  const int quad = lane >> 4, lr = lane & 15;
  const int wm = (wv >> 1) * 64, wn = (wv & 1) * 32;

  f32x4 accg[4][2], accv[4][2];
#pragma unroll
  for (int mi = 0; mi < 4; ++mi)
#pragma unroll
    for (int ni = 0; ni < 2; ++ni){
      accg[mi][ni] = (f32x4){0.f, 0.f, 0.f, 0.f};
      accv[mi][ni] = (f32x4){0.f, 0.f, 0.f, 0.f};
    }

  for (int kk = 0; kk < 64; ++kk){
    const int ko = kk * 32;
    __syncthreads();
    async_ld16(ap0 + ko, la0);
    async_ld16(ap1 + ko, la1);
    async_ld16(bg + ko, lbg);
    async_ld16(bv + ko, lbv);
    __syncthreads();
    short8 af[4], bgf[2], bvf[2];
#pragma unroll
    for (int mi = 0; mi < 4; ++mi)
      af[mi] = *(const short8*)&lA[(wm + mi*16 + lr) * 32 + quad * 8];
#pragma unroll
    for (int ni = 0; ni < 2; ++ni){
      bgf[ni] = *(const short8*)&lBg[(wn + ni*16 + lr) * 32 + quad * 8];
      bvf[ni] = *(const short8*)&lBv[(wn + ni*16 + lr) * 32 + quad * 8];
    }
#pragma unroll
    for (int mi = 0; mi < 4; ++mi)
#pragma unroll
      for (int ni = 0; ni < 2; ++ni){
        accg[mi][ni] = __builtin_amdgcn_mfma_f32_16x16x32_bf16(af[mi], bgf[ni], accg[mi][ni], 0, 0, 0);
        accv[mi][ni] = __builtin_amdgcn_mfma_f32_16x16x32_bf16(af[mi], bvf[ni], accv[mi][ni], 0, 0, 0);
      }
  }

#pragma unroll
  for (int mi = 0; mi < 4; ++mi)
#pragma unroll
    for (int ni = 0; ni < 2; ++ni)
#pragma unroll
      for (int r = 0; r < 4; ++r){
        int row = m0 + wm + mi*16 + quad*4 + r;
        if (row < Mvalid){
          int col = bx * 64 + wn + ni*16 + lr;
          float g = accg[mi][ni][r];
          float v = accv[mi][ni][r];
          float s = (g / (1.f + __expf(-g))) * v;
          act[(long)row * 2048 + col] = f2bf(s);
        }
      }
}

// GEMM2 (bf16 B): out = act @ W3^T; plain store or weighted scatter.
__global__ __launch_bounds__(256) void k_gemm2_bf(
    const unsigned short* __restrict__ A,
    const unsigned short* __restrict__ Bbase, long bstride,
    const int* __restrict__ seg, const int* __restrict__ tok,
    const float* __restrict__ aw,
    int Mvalid, float* __restrict__ out)
{
  __shared__ unsigned short lA[128*32];
  __shared__ unsigned short lB[128*32];
  const int tid = threadIdx.x;
  const int bx = blockIdx.x, by = blockIdx.y;
  const unsigned short* B = Bbase + (seg ? (long)seg[by] * bstride : 0L);
  const int m0 = by * 128;

  const int ar0 = m0 + (tid >> 2);
  const unsigned short* ap0 = A + (long)ar0 * 2048 + (tid & 3) * 8;
  const unsigned short* ap1 = ap0 + 64L * 2048;
  unsigned short* la0 = &lA[tid * 8];
  unsigned short* la1 = &lA[2048 + tid * 8];

  const unsigned short* bp0 = B + (long)(bx * 128 + (tid >> 2)) * 2048 + (tid & 3) * 8;
  const unsigned short* bp1 = bp0 + 64L * 2048;
  unsigned short* lb0 = &lB[tid * 8];
  unsigned short* lb1 = &lB[2048 + tid * 8];

  const int lane = tid & 63, wv = tid >> 6;
  const int quad = lane >> 4, lr = lane & 15;
  const int wm = (wv >> 1) * 64, wn = (wv & 1) * 64;

  f32x4 acc[4][4];
#pragma unroll
  for (int mi = 0; mi < 4; ++mi)
#pragma unroll
    for (int ni = 0; ni < 4; ++ni)
      acc[mi][ni] = (f32x4){0.f, 0.f, 0.f, 0.f};

  for (int kk = 0; kk < 64; ++kk){
    const int ko = kk * 32;
    __syncthreads();
    async_ld16(ap0 + ko, la0);
    async_ld16(ap1 + ko, la1);
    async_ld16(bp0 + ko, lb0);
    async_ld16(bp1 + ko, lb1);
    __syncthreads();
    short8 af[4], bf[4];
#pragma unroll
    for (int i = 0; i < 4; ++i){
      af[i] = *(const short8*)&lA[(wm + i*16 + lr) * 32 + quad * 8];
      bf[i] = *(const short8*)&lB[(wn + i*16 + lr) * 32 + quad * 8];
    }
#pragma unroll
    for (int mi = 0; mi < 4; ++mi)
#pragma unroll
      for (int ni = 0; ni < 4; ++ni)
        acc[mi][ni] = __builtin_amdgcn_mfma_f32_16x16x32_bf16(af[mi], bf[ni], acc[mi][ni], 0, 0, 0);
  }

#pragma unroll
  for (int mi = 0; mi < 4; ++mi)
#pragma unroll
    for (int r = 0; r < 4; ++r){
      const int row = m0 + wm + mi*16 + quad*4 + r;
      if (row >= Mvalid) continue;
      if (tok){
        float wgt = aw[row];
        if (wgt != 0.f){
          long orow = (long)tok[row] * 2048;
#pragma unroll
          for (int ni = 0; ni < 4; ++ni)
            atomicAdd(&out[orow + bx*128 + wn + ni*16 + lr], acc[mi][ni][r] * wgt);
        }
      } else {
#pragma unroll
        for (int ni = 0; ni < 4; ++ni)
          out[(long)row * 2048 + bx*128 + wn + ni*16 + lr] = acc[mi][ni][r];
      }
    }
}

// ======================= fallback: fp32-weight GEMM path ===================
__global__ __launch_bounds__(256) void k_gemm1(
    const unsigned short* __restrict__ A,
    const float* __restrict__ Bbase, long bstride,
    const int* __restrict__ seg, const int* __restrict__ tok,
    int Mvalid, unsigned short* __restrict__ act)
{
  __shared__ unsigned short lA[128*32];
  __shared__ unsigned short lBg[64*32];
  __shared__ unsigned short lBv[64*32];
  const int tid = threadIdx.x;
  const int bx = blockIdx.x, by = blockIdx.y;
  const float* B = Bbase + (seg ? (long)seg[by] * bstride : 0L);
  const int m0 = by * 128;

  const int ar0 = m0 + (tid >> 2), ar1 = ar0 + 64;
  const long gr0 = tok ? (long)tok[ar0] : (long)ar0;
  const long gr1 = tok ? (long)tok[ar1] : (long)ar1;
  const unsigned short* ap0 = A + gr0 * 2048 + (tid & 3) * 8;
  const unsigned short* ap1 = A + gr1 * 2048 + (tid & 3) * 8;
  unsigned short* la0 = &lA[tid * 8];
  unsigned short* la1 = &lA[2048 + tid * 8];

  const int brow = tid >> 3;
  const int bcol = (tid & 7) * 4;
  const float* bg = B + (long)(bx * 64 + brow) * 2048 + bcol;
  const float* bv = B + (long)(2048 + bx * 64 + brow) * 2048 + bcol;
  unsigned short* lbg = &lBg[brow * 32 + bcol];
  unsigned short* lbv = &lBv[brow * 32 + bcol];

  const int lane = tid & 63, wv = tid >> 6;
  const int quad = lane >> 4, lr = lane & 15;
  const int wm = (wv >> 1) * 64, wn = (wv & 1) * 32;

  f32x4 accg[4][2], accv[4][2];
#pragma unroll
  for (int mi = 0; mi < 4; ++mi)
#pragma unroll
    for (int ni = 0; ni < 2; ++ni){
      accg[mi][ni] = (f32x4){0.f, 0.f, 0.f, 0.f};
      accv[mi][ni] = (f32x4){0.f, 0.f, 0.f, 0.f};
    }

  for (int kk = 0; kk < 64; ++kk){
    const int ko = kk * 32;
    __syncthreads();
    async_ld16(ap0 + ko, la0);
    async_ld16(ap1 + ko, la1);
#pragma unroll
    for (int p = 0; p < 2; ++p){
      float4 g = *(const float4*)(bg + (long)p * 32 * 2048 + ko);
      float4 v = *(const float4*)(bv + (long)p * 32 * 2048 + ko);
      ushort4 gu, vu;
      gu.x = f2bf(g.x); gu.y = f2bf(g.y); gu.z = f2bf(g.z); gu.w = f2bf(g.w);
      vu.x = f2bf(v.x); vu.y = f2bf(v.y); vu.z = f2bf(v.z); vu.w = f2bf(v.w);
      *(ushort4*)(lbg + p * 1024) = gu;
      *(ushort4*)(lbv + p * 1024) = vu;
    }
    __syncthreads();
    short8 af[4], bgf[2], bvf[2];
#pragma unroll
    for (int mi = 0; mi < 4; ++mi)
      af[mi] = *(const short8*)&lA[(wm + mi*16 + lr) * 32 + quad * 8];
#pragma unroll
    for (int ni = 0; ni < 2; ++ni){
      bgf[ni] = *(const short8*)&lBg[(wn + ni*16 + lr) * 32 + quad * 8];
      bvf[ni] = *(const short8*)&lBv[(wn + ni*16 + lr) * 32 + quad * 8];
    }
#pragma unroll
    for (int mi = 0; mi < 4; ++mi)
#pragma unroll
      for (int ni = 0; ni < 2; ++ni){
        accg[mi][ni] = __builtin_amdgcn_mfma_f32_16x16x32_bf16(af[mi], bgf[ni], accg[mi][ni], 0, 0, 0);
        accv[mi][ni] = __builtin_amdgcn_mfma_f32_16x16x32_bf16(af[mi], bvf[ni], accv[mi][ni], 0, 0, 0);
      }
  }

#pragma unroll
  for (int mi = 0; mi < 4; ++mi)
#pragma unroll
    for (int ni = 0; ni < 2; ++ni)
#pragma unroll
      for (int r = 0; r < 4; ++r){
        int row = m0 + wm + mi*16 + quad*4 + r;
        if (row < Mvalid){
          int col = bx * 64 + wn + ni*16 + lr;
          float g = accg[mi][ni][r];
          float v = accv[mi][ni][r];
          float s = (g / (1.f + __expf(-g))) * v;
          act[(long)row * 2048 + col] = f2bf(s);
        }
      }
}

__global__ __launch_bounds__(256) void k_gemm2(
    const unsigned short* __restrict__ A,
    const float* __restrict__ Bbase, long bstride,
    const int* __restrict__ seg, const int* __restrict__ tok,
    const float* __restrict__ aw,
    int Mvalid, float* __restrict__ out)
{
  __shared__ unsigned short lA[128*32];
  __shared__ unsigned short lB[128*32];
  const int tid = threadIdx.x;
  const int bx = blockIdx.x, by = blockIdx.y;
  const float* B = Bbase + (seg ? (long)seg[by] * bstride : 0L);
  const int m0 = by * 128;

  const int ar0 = m0 + (tid >> 2);
  const unsigned short* ap0 = A + (long)ar0 * 2048 + (tid & 3) * 8;
  const unsigned short* ap1 = ap0 + 64L * 2048;
  unsigned short* la0 = &lA[tid * 8];
  unsigned short* la1 = &lA[2048 + tid * 8];

  const int brow = tid >> 3;
  const int bcol = (tid & 7) * 4;
  const float* bp = B + (long)(bx * 128 + brow) * 2048 + bcol;
  unsigned short* lb = &lB[brow * 32 + bcol];

  const int lane = tid & 63, wv = tid >> 6;
  const int quad = lane >> 4, lr = lane & 15;
  const int wm = (wv >> 1) * 64, wn = (wv & 1) * 64;

  f32x4 acc[4][4];
#pragma unroll
  for (int mi = 0; mi < 4; ++mi)
#pragma unroll
    for (int ni = 0; ni < 4; ++ni)
      acc[mi][ni] = (f32x4){0.f, 0.f, 0.f, 0.f};

  for (int kk = 0; kk < 64; ++kk){
    const int ko = kk * 32;
    __syncthreads();
    async_ld16(ap0 + ko, la0);
    async_ld16(ap1 + ko, la1);
#pragma unroll
    for (int p = 0; p < 4; ++p){
      float4 b4 = *(const float4*)(bp + (long)p * 32 * 2048 + ko);
      ushort4 bu;
      bu.x = f2bf(b4.x); bu.y = f2bf(b4.y); bu.z = f2bf(b4.z); bu.w = f2bf(b4.w);
      *(ushort4*)(lb + p * 1024) = bu;
    }
    __syncthreads();
    short8 af[4], bf[4];
#pragma unroll
    for (int i = 0; i < 4; ++i){
      af[i] = *(const short8*)&lA[(wm + i*16 + lr) * 32 + quad * 8];
      bf[i] = *(const short8*)&lB[(wn + i*16 + lr) * 32 + quad * 8];
    }
#pragma unroll
    for (int mi = 0; mi < 4; ++mi)
#pragma unroll
      for (int ni = 0; ni < 4; ++ni)
        acc[mi][ni] = __builtin_amdgcn_mfma_f32_16x16x32_bf16(af[mi], bf[ni], acc[mi][ni], 0, 0, 0);
  }

#pragma unroll
  for (int mi = 0; mi < 4; ++mi)
#pragma unroll
    for (int r = 0; r < 4; ++r){
      const int row = m0 + wm + mi*16 + quad*4 + r;
      if (row >= Mvalid) continue;
      if (tok){
        float wgt = aw[row];
        if (wgt != 0.f){
          long orow = (long)tok[row] * 2048;
#pragma unroll
          for (int ni = 0; ni < 4; ++ni)
            atomicAdd(&out[orow + bx*128 + wn + ni*16 + lr], acc[mi][ni][r] * wgt);
        }
      } else {
#pragma unroll
        for (int ni = 0; ni < 4; ++ni)
          out[(long)row * 2048 + bx*128 + wn + ni*16 + lr] = acc[mi][ni][r];
      }
    }
}

// ---------------- final RMSNorm in-place on out + aux_loss ----------------
__global__ __launch_bounds__(256) void k_final(
    float* __restrict__ out, const float* __restrict__ w)
{
  const int row = blockIdx.x, tid = threadIdx.x;
  float* o = out + (long)row * 2048;
  float4 a = ((const float4*)o)[tid];
  float4 b = ((const float4*)o)[tid + 256];
  float ss = a.x*a.x + a.y*a.y + a.z*a.z + a.w*a.w
           + b.x*b.x + b.y*b.y + b.z*b.z + b.w*b.w;
  ss = block_sum256(ss);
  float sc = rsqrtf(ss * (1.f / 2048.f) + 1e-6f);
  float4 wa = ((const float4*)w)[tid];
  float4 wb = ((const float4*)w)[tid + 256];
  float4 oa = {a.x*sc*wa.x, a.y*sc*wa.y, a.z*sc*wa.z, a.w*sc*wa.w};
  float4 ob = {b.x*sc*wb.x, b.y*sc*wb.y, b.z*sc*wb.z, b.w*sc*wb.w};
  ((float4*)o)[tid] = oa;
  ((float4*)o)[tid + 256] = ob;
  if (row == 0 && tid == 0) out[24576000L] = 0.f;
}

extern "C" void kernel_launch(void* const* d_in, const int* in_sizes, int n_in,
                              void* d_out, int out_size, void* d_ws, size_t ws_size,
                              hipStream_t stream)
{
  const float* x        = (const float*)d_in[0];
  const float* ln_pre   = (const float*)d_in[1];
  const float* ln_post  = (const float*)d_in[2];
  const float* router_w = (const float*)d_in[3];
  const float* sw12     = (const float*)d_in[4];
  const float* sw3      = (const float*)d_in[5];
  const float* ew12     = (const float*)d_in[6];
  const float* ew3      = (const float*)d_in[7];
  const float* eload    = (const float*)d_in[8];
  float* out = (float*)d_out;
  char*  ws  = (char*)d_ws;

  // ws layout (all 256B aligned)
  unsigned short* norm_x = (unsigned short*)(ws);                  // 12032*2048*2 = 49,283,072
  unsigned short* act    = (unsigned short*)(ws + 49283072L);      // 25088*2048*2 = 102,760,448
  float* rwn             = (float*)(ws + 152043520L);              // 65,536
  int*   t2i             = (int*)  (ws + 152109056L);              // 96,256
  float* t2w             = (float*)(ws + 152205312L);              // 96,256
  int*   atok            = (int*)  (ws + 152301568L);              // 100,352
  float* awt             = (float*)(ws + 152401920L);              // 100,352
  int*   seg             = (int*)  (ws + 152502272L);              // 1,024
  // bf16 weight copies (only used if workspace is large enough)
  unsigned short* bw12s  = (unsigned short*)(ws + 152503296L);     // 16,777,216
  unsigned short* bw3s   = (unsigned short*)(ws + 169280512L);     //  8,388,608
  unsigned short* bew12  = (unsigned short*)(ws + 177669120L);     // 134,217,728
  unsigned short* bew3   = (unsigned short*)(ws + 311886848L);     // 67,108,864
  const bool use_bf = ws_size >= 378995712UL;

  k_prep_router<<<dim3(8),     dim3(256), 0, stream>>>(router_w, rwn);
  k_rmsnorm_pre<<<dim3(12000), dim3(256), 0, stream>>>(x, ln_pre, norm_x);
  k_router     <<<dim3(750),   dim3(256), 0, stream>>>(x, ln_pre, rwn, eload, t2i, t2w);
  k_build_assign<<<dim3(1),    dim3(256), 0, stream>>>(t2i, t2w, atok, awt, seg);

  if (use_bf){
    // one-time fp32->bf16 weight conversion (numerics identical to in-loop f2bf)
    k_cvt<<<dim3(2048), dim3(256), 0, stream>>>((const float4*)sw12, (ushort4*)bw12s, 4096*2048/4);
    k_cvt<<<dim3(2048), dim3(256), 0, stream>>>((const float4*)sw3,  (ushort4*)bw3s,  2048*2048/4);
    k_cvt<<<dim3(2048), dim3(256), 0, stream>>>((const float4*)ew12, (ushort4*)bew12, 8*4096*2048/4);
    k_cvt<<<dim3(2048), dim3(256), 0, stream>>>((const float4*)ew3,  (ushort4*)bew3,  8*2048*2048/4);

    // shared expert
    k_gemm1_bf<<<dim3(32, 94), dim3(256), 0, stream>>>(
        norm_x, bw12s, 0L, (const int*)nullptr, (const int*)nullptr, NTOK, act);
    k_gemm2_bf<<<dim3(16, 94), dim3(256), 0, stream>>>(
        act, bw3s, 0L, (const int*)nullptr, (const int*)nullptr, (const float*)nullptr, NTOK, out);

    // routed experts (grouped over padded assignment segments)
    k_gemm1_bf<<<dim3(32, NRB), dim3(256), 0, stream>>>(
        norm_x, bew12, (long)4096 * 2048, seg, atok, APAD, act);
    k_gemm2_bf<<<dim3(16, NRB), dim3(256), 0, stream>>>(
        act, bew3, (long)2048 * 2048, seg, atok, awt, APAD, out);
  } else {
    // fallback: fp32 weights staged+converted in-loop (previous best path)
    k_gemm1<<<dim3(32, 94), dim3(256), 0, stream>>>(
        norm_x, sw12, 0L, (const int*)nullptr, (const int*)nullptr, NTOK, act);
    k_gemm2<<<dim3(16, 94), dim3(256), 0, stream>>>(
        act, sw3, 0L, (const int*)nullptr, (const int*)nullptr, (const float*)nullptr, NTOK, out);
    k_gemm1<<<dim3(32, NRB), dim3(256), 0, stream>>>(
        norm_x, ew12, (long)4096 * 2048, seg, atok, APAD, act);
    k_gemm2<<<dim3(16, NRB), dim3(256), 0, stream>>>(
        act, ew3, (long)2048 * 2048, seg, atok, awt, APAD, out);
  }

  k_final<<<dim3(12000), dim3(256), 0, stream>>>(out, ln_post);
}